// Round 2
// baseline (418.661 us; speedup 1.0000x reference)
//
#include <hip/hip_runtime.h>
#include <hip/hip_bf16.h>

#define LLSZ 65536  // L*L

// B=2, L=256, SD=64, PD=32, H=4, HD=16, OH=32, EXP=64, SE=16

// ---------- K0: prep G[d,e,p] = g_opm[de]*Wproj[de,p], GW[p], BW[p] ----------
__global__ __launch_bounds__(1024) void k0_prep(
    const float* __restrict__ g_opm, const float* __restrict__ b_opm,
    const float* __restrict__ Wproj, const float* __restrict__ b_proj,
    float* __restrict__ G, float* __restrict__ GW, float* __restrict__ BW)
{
    int de = threadIdx.x;  // 0..1023
    float g = g_opm[de];
    for (int p = 0; p < 32; ++p) G[de * 32 + p] = g * Wproj[de * 32 + p];
    __syncthreads();
    if (de < 32) {
        int p = de;
        float gw = 0.f, bw = 0.f;
        for (int k = 0; k < 1024; ++k) {
            gw += G[k * 32 + p];
            bw += b_opm[k] * Wproj[k * 32 + p];
        }
        GW[p] = gw;
        BW[p] = bw + b_proj[p];
    }
}

// ---------- K1: seq LN -> a (+row stats) and qkv ----------
__global__ __launch_bounds__(64) void k1_seq(
    const float* __restrict__ seq, const float* __restrict__ g_attn,
    const float* __restrict__ b_attn, const float* __restrict__ W_lin,
    const float* __restrict__ b_lin, const float* __restrict__ W_qkv,
    float* __restrict__ a, float* __restrict__ am, float* __restrict__ s2,
    float* __restrict__ qkv)
{
    int row = blockIdx.x;  // b*256 + i
    int t = threadIdx.x;   // 0..63
    float v = seq[row * 64 + t];
    float m = v;
    for (int k = 32; k > 0; k >>= 1) m += __shfl_xor(m, k, 64);
    m *= (1.f / 64.f);
    float d = v - m;
    float var = d * d;
    for (int k = 32; k > 0; k >>= 1) var += __shfl_xor(var, k, 64);
    var *= (1.f / 64.f);
    float x = d * rsqrtf(var + 1e-5f) * g_attn[t] + b_attn[t];
    __shared__ float xL[64];
    xL[t] = x;
    __syncthreads();
    if (t < 32) {
        float s = 0.f;
        for (int dd = 0; dd < 64; ++dd) s += xL[dd] * W_lin[dd * 32 + t];
        s += b_lin[t];
        a[row * 32 + t] = s;
        float mm = s, ss = s * s;
        for (int k = 16; k > 0; k >>= 1) {
            mm += __shfl_xor(mm, k, 32);
            ss += __shfl_xor(ss, k, 32);
        }
        if (t == 0) { am[row] = mm * (1.f / 32.f); s2[row] = ss * (1.f / 32.f); }
    }
    for (int c3 = 0; c3 < 3; ++c3) {
        int c = c3 * 64 + t;
        float s = 0.f;
        for (int dd = 0; dd < 64; ++dd) s += xL[dd] * W_qkv[dd * 192 + c];
        qkv[row * 192 + c] = s;
    }
}

// ---------- K2: T[row, e*32+p] = sum_d a[row,d]*G[d*1024 + e*32+p] ----------
__global__ __launch_bounds__(256) void k2_T(
    const float* __restrict__ a, const float* __restrict__ G, float* __restrict__ T)
{
    int row = blockIdx.x;
    int tid = threadIdx.x;
    __shared__ float aL[32];
    if (tid < 32) aL[tid] = a[row * 32 + tid];
    __syncthreads();
    for (int k = 0; k < 4; ++k) {
        int idx = k * 256 + tid;
        float s = 0.f;
        for (int d = 0; d < 32; ++d) s += aL[d] * G[d * 1024 + idx];
        T[row * 1024 + idx] = s;
    }
}

// ---------- K3: op + pair1 = pair_repr+op, pn = LN(pair1) ----------
__global__ __launch_bounds__(256) void k3_op(
    const float* __restrict__ a, const float* __restrict__ am,
    const float* __restrict__ s2, const float* __restrict__ T,
    const float* __restrict__ GW, const float* __restrict__ BW,
    const float* __restrict__ pair_in, const float* __restrict__ g_pair,
    const float* __restrict__ b_pair, float* __restrict__ pair1,
    float* __restrict__ pn)
{
    int row = blockIdx.x;  // b*256 + i
    int b = row >> 8;
    int tid = threadIdx.x;
    __shared__ float Tl[1024];
    __shared__ float aL[256];
    for (int k = 0; k < 4; ++k) Tl[k * 256 + tid] = T[(long)row * 1024 + k * 256 + tid];
    float am_i = am[row], s2_i = s2[row];
    int jj = tid >> 5, p = tid & 31;
    float gw = GW[p], bw = BW[p], gp = g_pair[p], bp = b_pair[p];
    for (int jt = 0; jt < 32; ++jt) {
        __syncthreads();
        aL[tid] = a[(b * 256 + jt * 8) * 32 + tid];
        __syncthreads();
        int j = jt * 8 + jj;
        float am_j = am[b * 256 + j], s2_j = s2[b * 256 + j];
        float S = 0.f;
        for (int e = 0; e < 32; ++e) S += aL[jj * 32 + e] * Tl[e * 32 + p];
        float m = am_i * am_j;
        float var = s2_i * s2_j - m * m;
        float isd = rsqrtf(var + 1e-5f);
        float op = isd * (S - m * gw) + bw;
        long idx = (long)row * 8192 + jt * 256 + tid;
        float pv = pair_in[idx] + op;
        pair1[idx] = pv;
        float mu = pv;
        for (int k = 16; k > 0; k >>= 1) mu += __shfl_xor(mu, k, 32);
        mu *= (1.f / 32.f);
        float dd = pv - mu;
        float vv = dd * dd;
        for (int k = 16; k > 0; k >>= 1) vv += __shfl_xor(vv, k, 32);
        vv *= (1.f / 32.f);
        pn[idx] = dd * rsqrtf(vv + 1e-5f) * gp + bp;
    }
}

// ---------- K4: expansion conv1x1: e1[b,o,pix] = sum_c pn[b,pix,c]*W_exp[o,c] ----------
__global__ __launch_bounds__(256) void k4_expand(
    const float* __restrict__ pn, const float* __restrict__ W_exp,
    float* __restrict__ e1)
{
    int blk = blockIdx.x;
    int b = blk >> 8;
    int pixbase = (blk & 255) * 256;
    int tid = threadIdx.x;
    __shared__ float pnL[256 * 33];
    __shared__ float We[64 * 32];
    for (int k = 0; k < 32; ++k) {
        int idx = k * 256 + tid;
        float v = pn[(long)b * LLSZ * 32 + (long)pixbase * 32 + idx];
        int pix = idx >> 5, c = idx & 31;
        pnL[pix * 33 + c] = v;
    }
    for (int k = 0; k < 8; ++k) We[k * 256 + tid] = W_exp[k * 256 + tid];
    __syncthreads();
    for (int o = 0; o < 64; ++o) {
        float s = 0.f;
        for (int c = 0; c < 32; ++c) s += pnL[tid * 33 + c] * We[o * 32 + c];
        e1[(long)(b * 64 + o) * LLSZ + pixbase + tid] = s;
    }
}

// ---------- generic per-channel instance-norm stats over 65536 pixels ----------
__global__ __launch_bounds__(256) void k_stats(
    const float* __restrict__ buf, float* __restrict__ m_out, float* __restrict__ isd_out)
{
    int chan = blockIdx.x;
    int tid = threadIdx.x;
    const float* p = buf + (long)chan * LLSZ;
    float s = 0.f, ss = 0.f;
    for (int k = 0; k < 256; ++k) {
        float v = p[k * 256 + tid];
        s += v; ss += v * v;
    }
    __shared__ float rs[256], rss[256];
    rs[tid] = s; rss[tid] = ss;
    __syncthreads();
    for (int k = 128; k > 0; k >>= 1) {
        if (tid < k) { rs[tid] += rs[tid + k]; rss[tid] += rss[tid + k]; }
        __syncthreads();
    }
    if (tid == 0) {
        float m = rs[0] * (1.f / 65536.f);
        float var = rss[0] * (1.f / 65536.f) - m * m;
        m_out[chan] = m;
        isd_out[chan] = rsqrtf(var + 1e-5f);
    }
}

// ---------- K6: depthwise 3x3 conv on silu(inorm(e1)) -> h2 ----------
__global__ __launch_bounds__(256) void k6_dw(
    const float* __restrict__ e1, const float* __restrict__ m1,
    const float* __restrict__ isd1, const float* __restrict__ W_dw,
    float* __restrict__ h2)
{
    int blk = blockIdx.x;
    int chan = blk >> 6;   // 0..127
    int tile = blk & 63;
    int i0 = (tile >> 3) * 32, j0 = (tile & 7) * 32;
    int o = chan & 63;
    int tid = threadIdx.x;
    float m = m1[chan], isd = isd1[chan];
    __shared__ float hT[34 * 34];
    const float* src = e1 + (long)chan * LLSZ;
    for (int idx = tid; idx < 1156; idx += 256) {
        int li = idx / 34, lj = idx % 34;
        int gi = i0 + li - 1, gj = j0 + lj - 1;
        float v = 0.f;
        if (gi >= 0 && gi < 256 && gj >= 0 && gj < 256) {
            float t = (src[gi * 256 + gj] - m) * isd;
            v = t / (1.f + expf(-t));
        }
        hT[idx] = v;
    }
    float w[9];
    for (int k = 0; k < 9; ++k) w[k] = W_dw[o * 9 + k];
    __syncthreads();
    for (int q = 0; q < 4; ++q) {
        int pix = q * 256 + tid;
        int li = pix >> 5, lj = pix & 31;
        float s = 0.f;
        for (int ki = 0; ki < 3; ++ki)
            for (int kj = 0; kj < 3; ++kj)
                s += hT[(li + ki) * 34 + lj + kj] * w[ki * 3 + kj];
        h2[(long)chan * LLSZ + (i0 + li) * 256 + j0 + lj] = s;
    }
}

// ---------- K8: squeeze = mean over pixels of silu(inorm(h2)) ----------
__global__ __launch_bounds__(256) void k8_squeeze(
    const float* __restrict__ h2, const float* __restrict__ m2,
    const float* __restrict__ isd2, float* __restrict__ sqmean)
{
    int chan = blockIdx.x;
    int tid = threadIdx.x;
    float m = m2[chan], isd = isd2[chan];
    const float* p = h2 + (long)chan * LLSZ;
    float s = 0.f;
    for (int k = 0; k < 256; ++k) {
        float t = (p[k * 256 + tid] - m) * isd;
        s += t / (1.f + expf(-t));
    }
    __shared__ float rs[256];
    rs[tid] = s;
    __syncthreads();
    for (int k = 128; k > 0; k >>= 1) {
        if (tid < k) rs[tid] += rs[tid + k];
        __syncthreads();
    }
    if (tid == 0) sqmean[chan] = rs[0] * (1.f / 65536.f);
}

// ---------- K9: SE MLP -> per-channel sigmoid scale sqv[b*64+c] ----------
__global__ __launch_bounds__(128) void k9_se(
    const float* __restrict__ sqmean, const float* __restrict__ W1,
    const float* __restrict__ b1, const float* __restrict__ W2,
    const float* __restrict__ b2, float* __restrict__ sqv)
{
    __shared__ float s1[2 * 16];
    int tid = threadIdx.x;
    if (tid < 32) {
        int b = tid >> 4, o = tid & 15;
        float s = 0.f;
        for (int c = 0; c < 64; ++c) s += sqmean[b * 64 + c] * W1[o * 64 + c];
        s += b1[o];
        s1[b * 16 + o] = s / (1.f + expf(-s));
    }
    __syncthreads();
    int b = tid >> 6, c = tid & 63;
    float s = 0.f;
    for (int j = 0; j < 16; ++j) s += s1[b * 16 + j] * W2[c * 16 + j];
    s += b2[c];
    sqv[b * 64 + c] = 1.f / (1.f + expf(-s));
}

// ---------- K10: pointwise conv: hp[b,p,pix] = sum_c g(h2)*W_pw[p,c] ----------
__global__ __launch_bounds__(256) void k10_pw(
    const float* __restrict__ h2, const float* __restrict__ m2,
    const float* __restrict__ isd2, const float* __restrict__ sqv,
    const float* __restrict__ W_pw, float* __restrict__ hp)
{
    int blk = blockIdx.x;
    int b = blk >> 8;
    int pixbase = (blk & 255) * 256;
    int tid = threadIdx.x;
    __shared__ float hL[32 * 256];
    __shared__ float Wp[32 * 64];
    for (int k = 0; k < 8; ++k) Wp[k * 256 + tid] = W_pw[k * 256 + tid];
    float acc[32];
    for (int p = 0; p < 32; ++p) acc[p] = 0.f;
    for (int half = 0; half < 2; ++half) {
        __syncthreads();
        for (int c = 0; c < 32; ++c) {
            int chan = b * 64 + half * 32 + c;
            float v = h2[(long)chan * LLSZ + pixbase + tid];
            float t = (v - m2[chan]) * isd2[chan];
            hL[c * 256 + tid] = (t / (1.f + expf(-t))) * sqv[chan];
        }
        __syncthreads();
        for (int p = 0; p < 32; ++p) {
            float s = 0.f;
            for (int c = 0; c < 32; ++c) s += hL[c * 256 + tid] * Wp[p * 64 + half * 32 + c];
            acc[p] += s;
        }
    }
    for (int p = 0; p < 32; ++p)
        hp[(long)(b * 32 + p) * LLSZ + pixbase + tid] = acc[p];
}

// ---------- K12: pair_out = pair1 + pn + inorm(hp); pn2=LN; bias = pn2@W_bias ----------
__global__ __launch_bounds__(256) void k12_merge(
    const float* __restrict__ pair1, const float* __restrict__ pn,
    const float* __restrict__ hp, const float* __restrict__ m3,
    const float* __restrict__ isd3, const float* __restrict__ g_pair,
    const float* __restrict__ b_pair, const float* __restrict__ W_bias,
    float* __restrict__ pair_out, float* __restrict__ biasbuf)
{
    int blk = blockIdx.x;
    int b = blk >> 8;
    int pixbase = (blk & 255) * 256;
    int tid = threadIdx.x;
    __shared__ float hpL[32 * 257];
    for (int p = 0; p < 32; ++p) {
        int chan = b * 32 + p;
        float v = hp[(long)chan * LLSZ + pixbase + tid];
        hpL[p * 257 + tid] = (v - m3[chan]) * isd3[chan];
    }
    __syncthreads();
    int jj = tid >> 5, p = tid & 31;
    float gp = g_pair[p], bp = b_pair[p];
    float wb0 = W_bias[p * 4 + 0], wb1 = W_bias[p * 4 + 1];
    float wb2 = W_bias[p * 4 + 2], wb3 = W_bias[p * 4 + 3];
    for (int it = 0; it < 32; ++it) {
        int pix = it * 8 + jj;
        long idx = (long)b * LLSZ * 32 + (long)(pixbase + pix) * 32 + p;
        float v = pair1[idx] + pn[idx] + hpL[p * 257 + pix];
        pair_out[idx] = v;
        float mu = v;
        for (int k = 16; k > 0; k >>= 1) mu += __shfl_xor(mu, k, 32);
        mu *= (1.f / 32.f);
        float d = v - mu;
        float vv = d * d;
        for (int k = 16; k > 0; k >>= 1) vv += __shfl_xor(vv, k, 32);
        vv *= (1.f / 32.f);
        float pn2 = d * rsqrtf(vv + 1e-5f) * gp + bp;
        float t0 = pn2 * wb0, t1 = pn2 * wb1, t2 = pn2 * wb2, t3 = pn2 * wb3;
        for (int k = 16; k > 0; k >>= 1) {
            t0 += __shfl_xor(t0, k, 32);
            t1 += __shfl_xor(t1, k, 32);
            t2 += __shfl_xor(t2, k, 32);
            t3 += __shfl_xor(t3, k, 32);
        }
        if (p == 0) {
            int ij = pixbase + pix;
            biasbuf[(long)(b * 4 + 0) * LLSZ + ij] = t0;
            biasbuf[(long)(b * 4 + 1) * LLSZ + ij] = t1;
            biasbuf[(long)(b * 4 + 2) * LLSZ + ij] = t2;
            biasbuf[(long)(b * 4 + 3) * LLSZ + ij] = t3;
        }
    }
}

// ---------- K13: attention per (b,h,i) ----------
__global__ __launch_bounds__(256) void k13_attn(
    const float* __restrict__ qkv, const float* __restrict__ biasbuf,
    float* __restrict__ ctx)
{
    int blk = blockIdx.x;
    int i = blk & 255;
    int h = (blk >> 8) & 3;
    int b = blk >> 10;
    int tid = threadIdx.x;
    __shared__ float qL[16];
    __shared__ float red[256];
    __shared__ float wL[256];
    __shared__ float pL[256];
    if (tid < 16) qL[tid] = qkv[(long)(b * 256 + i) * 192 + h * 16 + tid];
    __syncthreads();
    const float* krow = qkv + (long)(b * 256 + tid) * 192 + 64 + h * 16;
    float s = 0.f;
    for (int d = 0; d < 16; ++d) s += qL[d] * krow[d];
    s = s * 0.25f + biasbuf[(long)(b * 4 + h) * LLSZ + i * 256 + tid];
    red[tid] = s;
    __syncthreads();
    for (int k = 128; k > 0; k >>= 1) {
        if (tid < k) red[tid] = fmaxf(red[tid], red[tid + k]);
        __syncthreads();
    }
    float mx = red[0];
    __syncthreads();
    float w = expf(s - mx);
    wL[tid] = w;
    red[tid] = w;
    __syncthreads();
    for (int k = 128; k > 0; k >>= 1) {
        if (tid < k) red[tid] += red[tid + k];
        __syncthreads();
    }
    float inv = 1.f / red[0];
    int d = tid & 15, jg = tid >> 4;
    const float* vbase = qkv + 128 + h * 16 + d;
    float ps = 0.f;
    for (int jjj = 0; jjj < 16; ++jjj) {
        int jn = jg * 16 + jjj;
        ps += wL[jn] * vbase[(long)(b * 256 + jn) * 192];
    }
    pL[tid] = ps;
    __syncthreads();
    if (tid < 16) {
        float c = 0.f;
        for (int jg2 = 0; jg2 < 16; ++jg2) c += pL[jg2 * 16 + tid];
        ctx[(long)(b * 256 + i) * 64 + h * 16 + tid] = c * inv;
    }
}

// ---------- K14: seq_out = seq + ctx@W_outp + b_outp ----------
__global__ __launch_bounds__(64) void k14_seqout(
    const float* __restrict__ seq, const float* __restrict__ ctx,
    const float* __restrict__ W_outp, const float* __restrict__ b_outp,
    float* __restrict__ out)
{
    int row = blockIdx.x;
    int t = threadIdx.x;
    __shared__ float cL[64];
    cL[t] = ctx[row * 64 + t];
    __syncthreads();
    float s = b_outp[t];
    for (int u = 0; u < 64; ++u) s += cL[u] * W_outp[u * 64 + t];
    out[row * 64 + t] = seq[row * 64 + t] + s;
}

extern "C" void kernel_launch(void* const* d_in, const int* in_sizes, int n_in,
                              void* d_out, int out_size, void* d_ws, size_t ws_size,
                              hipStream_t stream) {
    const float* seq_repr   = (const float*)d_in[0];
    const float* pair_repr  = (const float*)d_in[1];
    const float* g_attn     = (const float*)d_in[2];
    const float* b_attn     = (const float*)d_in[3];
    const float* g_pair     = (const float*)d_in[4];
    const float* b_pair     = (const float*)d_in[5];
    const float* W_opm_lin  = (const float*)d_in[6];
    const float* b_opm_lin  = (const float*)d_in[7];
    const float* g_opm      = (const float*)d_in[8];
    const float* b_opm      = (const float*)d_in[9];
    const float* W_opm_proj = (const float*)d_in[10];
    const float* b_opm_proj = (const float*)d_in[11];
    const float* W_exp      = (const float*)d_in[12];
    const float* W_dw       = (const float*)d_in[13];
    const float* W_se1      = (const float*)d_in[14];
    const float* b_se1      = (const float*)d_in[15];
    const float* W_se2      = (const float*)d_in[16];
    const float* b_se2      = (const float*)d_in[17];
    const float* W_pw       = (const float*)d_in[18];
    const float* W_qkv      = (const float*)d_in[19];
    const float* W_outp     = (const float*)d_in[20];
    const float* b_outp     = (const float*)d_in[21];
    const float* W_bias     = (const float*)d_in[22];

    float* out_seq  = (float*)d_out;            // 2*256*64 = 32768
    float* out_pair = (float*)d_out + 32768;    // 2*256*256*32

    // Workspace layout (floats). Aliasing to cut peak footprint:
    //   hp  aliases e1   (e1 dead after k6_dw; hp written in k10_pw)
    //   biasb aliases T  (T dead after k3_op; biasb written in k12_merge)
    float* w = (float*)d_ws;
    float* a_buf   = w;                    // 16384
    float* am_buf  = a_buf + 16384;        // 512
    float* s2_buf  = am_buf + 512;         // 512
    float* qkv_buf = s2_buf + 512;         // 98304
    float* G_buf   = qkv_buf + 98304;      // 32768
    float* GW_buf  = G_buf + 32768;        // 32
    float* BW_buf  = GW_buf + 32;          // 32
    float* ctx     = BW_buf + 32;          // 32768
    float* st1m    = ctx + 32768;          // 128
    float* st1i    = st1m + 128;           // 128
    float* st2m    = st1i + 128;           // 128
    float* st2i    = st2m + 128;           // 128
    float* sqmean  = st2i + 128;           // 128
    float* sqv     = sqmean + 128;         // 128
    float* st3m    = sqv + 128;            // 64
    float* st3i    = st3m + 64;            // 64
    float* T_buf   = st3i + 64;            // 524288
    float* biasb   = T_buf;                // alias (T dead after k3)
    float* pair1   = T_buf + 524288;       // 4194304
    float* pn      = pair1 + 4194304;      // 4194304
    float* e1      = pn + 4194304;         // 8388608
    float* hp      = e1;                   // alias (e1 dead after k6; hp is 4194304)
    float* h2      = e1 + 8388608;         // 8388608
    // total: ~99 MB

    hipLaunchKernelGGL(k0_prep, dim3(1), dim3(1024), 0, stream,
                       g_opm, b_opm, W_opm_proj, b_opm_proj, G_buf, GW_buf, BW_buf);
    hipLaunchKernelGGL(k1_seq, dim3(512), dim3(64), 0, stream,
                       seq_repr, g_attn, b_attn, W_opm_lin, b_opm_lin, W_qkv,
                       a_buf, am_buf, s2_buf, qkv_buf);
    hipLaunchKernelGGL(k2_T, dim3(512), dim3(256), 0, stream, a_buf, G_buf, T_buf);
    hipLaunchKernelGGL(k3_op, dim3(512), dim3(256), 0, stream,
                       a_buf, am_buf, s2_buf, T_buf, GW_buf, BW_buf,
                       pair_repr, g_pair, b_pair, pair1, pn);
    hipLaunchKernelGGL(k4_expand, dim3(512), dim3(256), 0, stream, pn, W_exp, e1);
    hipLaunchKernelGGL(k_stats, dim3(128), dim3(256), 0, stream, e1, st1m, st1i);
    hipLaunchKernelGGL(k6_dw, dim3(8192), dim3(256), 0, stream, e1, st1m, st1i, W_dw, h2);
    hipLaunchKernelGGL(k_stats, dim3(128), dim3(256), 0, stream, h2, st2m, st2i);
    hipLaunchKernelGGL(k8_squeeze, dim3(128), dim3(256), 0, stream, h2, st2m, st2i, sqmean);
    hipLaunchKernelGGL(k9_se, dim3(1), dim3(128), 0, stream,
                       sqmean, W_se1, b_se1, W_se2, b_se2, sqv);
    hipLaunchKernelGGL(k10_pw, dim3(512), dim3(256), 0, stream,
                       h2, st2m, st2i, sqv, W_pw, hp);
    hipLaunchKernelGGL(k_stats, dim3(64), dim3(256), 0, stream, hp, st3m, st3i);
    hipLaunchKernelGGL(k12_merge, dim3(512), dim3(256), 0, stream,
                       pair1, pn, hp, st3m, st3i, g_pair, b_pair, W_bias,
                       out_pair, biasb);
    hipLaunchKernelGGL(k13_attn, dim3(2048), dim3(256), 0, stream, qkv_buf, biasb, ctx);
    hipLaunchKernelGGL(k14_seqout, dim3(512), dim3(64), 0, stream,
                       seq_repr, ctx, W_outp, b_outp, out_seq);
}

// Round 3
// 329.206 us; speedup vs baseline: 1.2717x; 1.2717x over previous
//
#include <hip/hip_runtime.h>
#include <hip/hip_bf16.h>

#define LLSZ 65536  // L*L
#define INV_LL (1.f / 65536.f)

// B=2, L=256, SD=64, PD=32, H=4, HD=16, OH=32, EXP=64, SE=16

// ---------- K0: prep G[d,e,p] = g_opm[de]*Wproj[de,p], GW[p], BW[p] ----------
// Parallel: thread (rg,p) sums 32 rows de = k*32+rg; LDS tree over rg.
__global__ __launch_bounds__(1024) void k0_prep(
    const float* __restrict__ g_opm, const float* __restrict__ b_opm,
    const float* __restrict__ Wproj, const float* __restrict__ b_proj,
    float* __restrict__ G, float* __restrict__ GW, float* __restrict__ BW)
{
    int tid = threadIdx.x;
    int p = tid & 31, rg = tid >> 5;  // rg 0..31
    float gw = 0.f, bw = 0.f;
    #pragma unroll 4
    for (int k = 0; k < 32; ++k) {
        int de = k * 32 + rg;
        float g = g_opm[de], b = b_opm[de];
        float wv = Wproj[de * 32 + p];
        float gv = g * wv;
        G[de * 32 + p] = gv;
        gw += gv;
        bw += b * wv;
    }
    __shared__ float rG[1024], rB[1024];
    rG[rg * 32 + p] = gw;
    rB[rg * 32 + p] = bw;
    __syncthreads();
    for (int s = 16; s > 0; s >>= 1) {
        if (rg < s) {
            rG[rg * 32 + p] += rG[(rg + s) * 32 + p];
            rB[rg * 32 + p] += rB[(rg + s) * 32 + p];
        }
        __syncthreads();
    }
    if (tid < 32) {
        GW[p] = rG[p];
        BW[p] = rB[p] + b_proj[p];
    }
}

// ---------- K1: seq LN -> a (+row stats) and qkv. 4 rows/block, weights in LDS ----------
__global__ __launch_bounds__(256) void k1_seq(
    const float* __restrict__ seq, const float* __restrict__ g_attn,
    const float* __restrict__ b_attn, const float* __restrict__ W_lin,
    const float* __restrict__ b_lin, const float* __restrict__ W_qkv,
    float* __restrict__ a, float* __restrict__ am, float* __restrict__ s2,
    float* __restrict__ qkv)
{
    __shared__ float Wq[64 * 192];   // 48 KB
    __shared__ float Wl[64 * 32];    // 8 KB
    __shared__ float xL[4][64];
    int tid = threadIdx.x;
    #pragma unroll
    for (int k = 0; k < 48; ++k) Wq[k * 256 + tid] = W_qkv[k * 256 + tid];
    #pragma unroll
    for (int k = 0; k < 8; ++k) Wl[k * 256 + tid] = W_lin[k * 256 + tid];

    int sub = tid >> 6, t = tid & 63;       // sub == wave id (waves are 64 threads)
    int row = blockIdx.x * 4 + sub;         // 0..511
    float v = seq[row * 64 + t];
    float m = v;
    for (int k = 32; k > 0; k >>= 1) m += __shfl_xor(m, k, 64);
    m *= (1.f / 64.f);
    float d = v - m;
    float var = d * d;
    for (int k = 32; k > 0; k >>= 1) var += __shfl_xor(var, k, 64);
    var *= (1.f / 64.f);
    float x = d * rsqrtf(var + 1e-5f) * g_attn[t] + b_attn[t];
    xL[sub][t] = x;
    __syncthreads();   // weights + xL visible to all

    if (t < 32) {
        float s = 0.f;
        #pragma unroll
        for (int dd = 0; dd < 64; ++dd) s += xL[sub][dd] * Wl[dd * 32 + t];
        s += b_lin[t];
        a[row * 32 + t] = s;
        float mm = s, ss = s * s;
        for (int k = 16; k > 0; k >>= 1) {
            mm += __shfl_xor(mm, k, 32);
            ss += __shfl_xor(ss, k, 32);
        }
        if (t == 0) { am[row] = mm * (1.f / 32.f); s2[row] = ss * (1.f / 32.f); }
    }
    #pragma unroll
    for (int c3 = 0; c3 < 3; ++c3) {
        int c = c3 * 64 + t;
        float s = 0.f;
        #pragma unroll
        for (int dd = 0; dd < 64; ++dd) s += xL[sub][dd] * Wq[dd * 192 + c];
        qkv[row * 192 + c] = s;
    }
}

// ---------- K2: T[row, e*32+p] = sum_d a[row,d]*G[d*1024 + e*32+p] ----------
__global__ __launch_bounds__(256) void k2_T(
    const float* __restrict__ a, const float* __restrict__ G, float* __restrict__ T)
{
    int row = blockIdx.x;
    int tid = threadIdx.x;
    __shared__ float aL[32];
    if (tid < 32) aL[tid] = a[row * 32 + tid];
    __syncthreads();
    for (int k = 0; k < 4; ++k) {
        int idx = k * 256 + tid;
        float s = 0.f;
        #pragma unroll
        for (int d = 0; d < 32; ++d) s += aL[d] * G[d * 1024 + idx];
        T[row * 1024 + idx] = s;
    }
}

// ---------- K3: op + pair1 = pair_repr+op, pn = LN(pair1) ----------
__global__ __launch_bounds__(256) void k3_op(
    const float* __restrict__ a, const float* __restrict__ am,
    const float* __restrict__ s2, const float* __restrict__ T,
    const float* __restrict__ GW, const float* __restrict__ BW,
    const float* __restrict__ pair_in, const float* __restrict__ g_pair,
    const float* __restrict__ b_pair, float* __restrict__ pair1,
    float* __restrict__ pn)
{
    int row = blockIdx.x;  // b*256 + i
    int b = row >> 8;
    int tid = threadIdx.x;
    __shared__ float Tl[1024];
    __shared__ float aL[256];
    for (int k = 0; k < 4; ++k) Tl[k * 256 + tid] = T[(long)row * 1024 + k * 256 + tid];
    float am_i = am[row], s2_i = s2[row];
    int jj = tid >> 5, p = tid & 31;
    float gw = GW[p], bw = BW[p], gp = g_pair[p], bp = b_pair[p];
    for (int jt = 0; jt < 32; ++jt) {
        __syncthreads();
        aL[tid] = a[(b * 256 + jt * 8) * 32 + tid];
        __syncthreads();
        int j = jt * 8 + jj;
        float am_j = am[b * 256 + j], s2_j = s2[b * 256 + j];
        float S = 0.f;
        #pragma unroll
        for (int e = 0; e < 32; ++e) S += aL[jj * 32 + e] * Tl[e * 32 + p];
        float m = am_i * am_j;
        float var = s2_i * s2_j - m * m;
        float isd = rsqrtf(var + 1e-5f);
        float op = isd * (S - m * gw) + bw;
        long idx = (long)row * 8192 + jt * 256 + tid;
        float pv = pair_in[idx] + op;
        pair1[idx] = pv;
        float mu = pv;
        for (int k = 16; k > 0; k >>= 1) mu += __shfl_xor(mu, k, 32);
        mu *= (1.f / 32.f);
        float dd = pv - mu;
        float vv = dd * dd;
        for (int k = 16; k > 0; k >>= 1) vv += __shfl_xor(vv, k, 32);
        vv *= (1.f / 32.f);
        pn[idx] = dd * rsqrtf(vv + 1e-5f) * gp + bp;
    }
}

// ---------- K4: expansion conv1x1: e1[b,o,pix] = sum_c pn[b,pix,c]*W_exp[o,c] ----------
__global__ __launch_bounds__(256) void k4_expand(
    const float* __restrict__ pn, const float* __restrict__ W_exp,
    float* __restrict__ e1)
{
    int blk = blockIdx.x;
    int b = blk >> 8;
    int pixbase = (blk & 255) * 256;
    int tid = threadIdx.x;
    __shared__ float pnL[256 * 33];
    __shared__ float We[64 * 32];
    for (int k = 0; k < 32; ++k) {
        int idx = k * 256 + tid;
        float v = pn[(long)b * LLSZ * 32 + (long)pixbase * 32 + idx];
        int pix = idx >> 5, c = idx & 31;
        pnL[pix * 33 + c] = v;
    }
    for (int k = 0; k < 8; ++k) We[k * 256 + tid] = W_exp[k * 256 + tid];
    __syncthreads();
    for (int o = 0; o < 64; ++o) {
        float s = 0.f;
        #pragma unroll
        for (int c = 0; c < 32; ++c) s += pnL[tid * 33 + c] * We[o * 32 + c];
        e1[(long)(b * 64 + o) * LLSZ + pixbase + tid] = s;
    }
}

// ---------- stats: per-channel sum/sumsq via 8 segments + atomics (bufs pre-zeroed) ----------
__global__ __launch_bounds__(256) void k_stats(
    const float* __restrict__ buf, float* __restrict__ sum, float* __restrict__ sumsq)
{
    int bid = blockIdx.x;
    int chan = bid >> 3, seg = bid & 7;
    int tid = threadIdx.x;
    const float4* p = (const float4*)(buf + (long)chan * LLSZ + seg * 8192);
    float s = 0.f, ss = 0.f;
    #pragma unroll
    for (int k = 0; k < 8; ++k) {
        float4 v = p[k * 256 + tid];
        s += v.x + v.y + v.z + v.w;
        ss += v.x * v.x + v.y * v.y + v.z * v.z + v.w * v.w;
    }
    for (int k = 32; k > 0; k >>= 1) { s += __shfl_xor(s, k, 64); ss += __shfl_xor(ss, k, 64); }
    __shared__ float rs[4], rq[4];
    int wave = tid >> 6;
    if ((tid & 63) == 0) { rs[wave] = s; rq[wave] = ss; }
    __syncthreads();
    if (tid == 0) {
        atomicAdd(&sum[chan], rs[0] + rs[1] + rs[2] + rs[3]);
        atomicAdd(&sumsq[chan], rq[0] + rq[1] + rq[2] + rq[3]);
    }
}

__device__ __forceinline__ void chan_stats(const float* sum, const float* sumsq,
                                           int chan, float& m, float& isd)
{
    m = sum[chan] * INV_LL;
    float var = sumsq[chan] * INV_LL - m * m;
    isd = rsqrtf(var + 1e-5f);
}

// ---------- K6: depthwise 3x3 conv on silu(inorm(e1)) -> h2 ----------
__global__ __launch_bounds__(256) void k6_dw(
    const float* __restrict__ e1, const float* __restrict__ st1s,
    const float* __restrict__ st1q, const float* __restrict__ W_dw,
    float* __restrict__ h2)
{
    int blk = blockIdx.x;
    int chan = blk >> 6;   // 0..127
    int tile = blk & 63;
    int i0 = (tile >> 3) * 32, j0 = (tile & 7) * 32;
    int o = chan & 63;
    int tid = threadIdx.x;
    float m, isd;
    chan_stats(st1s, st1q, chan, m, isd);
    __shared__ float hT[34 * 34];
    const float* src = e1 + (long)chan * LLSZ;
    for (int idx = tid; idx < 1156; idx += 256) {
        int li = idx / 34, lj = idx % 34;
        int gi = i0 + li - 1, gj = j0 + lj - 1;
        float v = 0.f;
        if (gi >= 0 && gi < 256 && gj >= 0 && gj < 256) {
            float t = (src[gi * 256 + gj] - m) * isd;
            v = t / (1.f + expf(-t));
        }
        hT[idx] = v;
    }
    float w[9];
    #pragma unroll
    for (int k = 0; k < 9; ++k) w[k] = W_dw[o * 9 + k];
    __syncthreads();
    for (int q = 0; q < 4; ++q) {
        int pix = q * 256 + tid;
        int li = pix >> 5, lj = pix & 31;
        float s = 0.f;
        #pragma unroll
        for (int ki = 0; ki < 3; ++ki)
            #pragma unroll
            for (int kj = 0; kj < 3; ++kj)
                s += hT[(li + ki) * 34 + lj + kj] * w[ki * 3 + kj];
        h2[(long)chan * LLSZ + (i0 + li) * 256 + j0 + lj] = s;
    }
}

// ---------- K8: squeeze sum of silu(inorm(h2)), 8 segments + atomics ----------
__global__ __launch_bounds__(256) void k8_squeeze(
    const float* __restrict__ h2, const float* __restrict__ st2s,
    const float* __restrict__ st2q, float* __restrict__ sqs)
{
    int bid = blockIdx.x;
    int chan = bid >> 3, seg = bid & 7;
    int tid = threadIdx.x;
    float m, isd;
    chan_stats(st2s, st2q, chan, m, isd);
    const float4* p = (const float4*)(h2 + (long)chan * LLSZ + seg * 8192);
    float s = 0.f;
    #pragma unroll
    for (int k = 0; k < 8; ++k) {
        float4 v = p[k * 256 + tid];
        float t;
        t = (v.x - m) * isd; s += t / (1.f + expf(-t));
        t = (v.y - m) * isd; s += t / (1.f + expf(-t));
        t = (v.z - m) * isd; s += t / (1.f + expf(-t));
        t = (v.w - m) * isd; s += t / (1.f + expf(-t));
    }
    for (int k = 32; k > 0; k >>= 1) s += __shfl_xor(s, k, 64);
    __shared__ float rs[4];
    int wave = tid >> 6;
    if ((tid & 63) == 0) rs[wave] = s;
    __syncthreads();
    if (tid == 0) atomicAdd(&sqs[chan], rs[0] + rs[1] + rs[2] + rs[3]);
}

// ---------- K9: SE MLP -> per-channel sigmoid scale sqv[b*64+c] ----------
__global__ __launch_bounds__(128) void k9_se(
    const float* __restrict__ sqs, const float* __restrict__ W1,
    const float* __restrict__ b1, const float* __restrict__ W2,
    const float* __restrict__ b2, float* __restrict__ sqv)
{
    __shared__ float s1[2 * 16];
    int tid = threadIdx.x;
    if (tid < 32) {
        int b = tid >> 4, o = tid & 15;
        float s = 0.f;
        for (int c = 0; c < 64; ++c) s += sqs[b * 64 + c] * W1[o * 64 + c];
        s = s * INV_LL + b1[o];
        s1[b * 16 + o] = s / (1.f + expf(-s));
    }
    __syncthreads();
    int b = tid >> 6, c = tid & 63;
    float s = 0.f;
    #pragma unroll
    for (int j = 0; j < 16; ++j) s += s1[b * 16 + j] * W2[c * 16 + j];
    s += b2[c];
    sqv[b * 64 + c] = 1.f / (1.f + expf(-s));
}

// ---------- K10: pointwise conv: hp[b,p,pix] = sum_c g(h2)*W_pw[p,c] ----------
__global__ __launch_bounds__(256) void k10_pw(
    const float* __restrict__ h2, const float* __restrict__ st2s,
    const float* __restrict__ st2q, const float* __restrict__ sqv,
    const float* __restrict__ W_pw, float* __restrict__ hp)
{
    int blk = blockIdx.x;
    int b = blk >> 8;
    int pixbase = (blk & 255) * 256;
    int tid = threadIdx.x;
    __shared__ float hL[32 * 256];
    __shared__ float Wp[32 * 64];
    for (int k = 0; k < 8; ++k) Wp[k * 256 + tid] = W_pw[k * 256 + tid];
    float acc[32];
    #pragma unroll
    for (int p = 0; p < 32; ++p) acc[p] = 0.f;
    for (int half = 0; half < 2; ++half) {
        __syncthreads();
        for (int c = 0; c < 32; ++c) {
            int chan = b * 64 + half * 32 + c;
            float m, isd;
            chan_stats(st2s, st2q, chan, m, isd);
            float v = h2[(long)chan * LLSZ + pixbase + tid];
            float t = (v - m) * isd;
            hL[c * 256 + tid] = (t / (1.f + expf(-t))) * sqv[chan];
        }
        __syncthreads();
        #pragma unroll
        for (int p = 0; p < 32; ++p) {
            float s = 0.f;
            #pragma unroll
            for (int c = 0; c < 32; ++c) s += hL[c * 256 + tid] * Wp[p * 64 + half * 32 + c];
            acc[p] += s;
        }
    }
    for (int p = 0; p < 32; ++p)
        hp[(long)(b * 32 + p) * LLSZ + pixbase + tid] = acc[p];
}

// ---------- K12: pair_out = pair1 + pn + inorm(hp); pn2=LN; bias = pn2@W_bias ----------
__global__ __launch_bounds__(256) void k12_merge(
    const float* __restrict__ pair1, const float* __restrict__ pn,
    const float* __restrict__ hp, const float* __restrict__ st3s,
    const float* __restrict__ st3q, const float* __restrict__ g_pair,
    const float* __restrict__ b_pair, const float* __restrict__ W_bias,
    float* __restrict__ pair_out, float* __restrict__ biasbuf)
{
    int blk = blockIdx.x;
    int b = blk >> 8;
    int pixbase = (blk & 255) * 256;
    int tid = threadIdx.x;
    __shared__ float hpL[32 * 257];
    for (int p = 0; p < 32; ++p) {
        int chan = b * 32 + p;
        float m, isd;
        chan_stats(st3s, st3q, chan, m, isd);
        float v = hp[(long)chan * LLSZ + pixbase + tid];
        hpL[p * 257 + tid] = (v - m) * isd;
    }
    __syncthreads();
    int jj = tid >> 5, p = tid & 31;
    float gp = g_pair[p], bp = b_pair[p];
    float wb0 = W_bias[p * 4 + 0], wb1 = W_bias[p * 4 + 1];
    float wb2 = W_bias[p * 4 + 2], wb3 = W_bias[p * 4 + 3];
    for (int it = 0; it < 32; ++it) {
        int pix = it * 8 + jj;
        long idx = (long)b * LLSZ * 32 + (long)(pixbase + pix) * 32 + p;
        float v = pair1[idx] + pn[idx] + hpL[p * 257 + pix];
        pair_out[idx] = v;
        float mu = v;
        for (int k = 16; k > 0; k >>= 1) mu += __shfl_xor(mu, k, 32);
        mu *= (1.f / 32.f);
        float d = v - mu;
        float vv = d * d;
        for (int k = 16; k > 0; k >>= 1) vv += __shfl_xor(vv, k, 32);
        vv *= (1.f / 32.f);
        float pn2 = d * rsqrtf(vv + 1e-5f) * gp + bp;
        float t0 = pn2 * wb0, t1 = pn2 * wb1, t2 = pn2 * wb2, t3 = pn2 * wb3;
        for (int k = 16; k > 0; k >>= 1) {
            t0 += __shfl_xor(t0, k, 32);
            t1 += __shfl_xor(t1, k, 32);
            t2 += __shfl_xor(t2, k, 32);
            t3 += __shfl_xor(t3, k, 32);
        }
        if (p == 0) {
            int ij = pixbase + pix;
            biasbuf[(long)(b * 4 + 0) * LLSZ + ij] = t0;
            biasbuf[(long)(b * 4 + 1) * LLSZ + ij] = t1;
            biasbuf[(long)(b * 4 + 2) * LLSZ + ij] = t2;
            biasbuf[(long)(b * 4 + 3) * LLSZ + ij] = t3;
        }
    }
}

// ---------- K13: attention per (b,h,i) ----------
__global__ __launch_bounds__(256) void k13_attn(
    const float* __restrict__ qkv, const float* __restrict__ biasbuf,
    float* __restrict__ ctx)
{
    int blk = blockIdx.x;
    int i = blk & 255;
    int h = (blk >> 8) & 3;
    int b = blk >> 10;
    int tid = threadIdx.x;
    __shared__ float qL[16];
    __shared__ float red[256];
    __shared__ float wL[256];
    __shared__ float pL[256];
    if (tid < 16) qL[tid] = qkv[(long)(b * 256 + i) * 192 + h * 16 + tid];
    __syncthreads();
    const float* krow = qkv + (long)(b * 256 + tid) * 192 + 64 + h * 16;
    float s = 0.f;
    #pragma unroll
    for (int d = 0; d < 16; ++d) s += qL[d] * krow[d];
    s = s * 0.25f + biasbuf[(long)(b * 4 + h) * LLSZ + i * 256 + tid];
    red[tid] = s;
    __syncthreads();
    for (int k = 128; k > 0; k >>= 1) {
        if (tid < k) red[tid] = fmaxf(red[tid], red[tid + k]);
        __syncthreads();
    }
    float mx = red[0];
    __syncthreads();
    float w = expf(s - mx);
    wL[tid] = w;
    red[tid] = w;
    __syncthreads();
    for (int k = 128; k > 0; k >>= 1) {
        if (tid < k) red[tid] += red[tid + k];
        __syncthreads();
    }
    float inv = 1.f / red[0];
    int d = tid & 15, jg = tid >> 4;
    const float* vbase = qkv + 128 + h * 16 + d;
    float ps = 0.f;
    #pragma unroll
    for (int jjj = 0; jjj < 16; ++jjj) {
        int jn = jg * 16 + jjj;
        ps += wL[jn] * vbase[(long)(b * 256 + jn) * 192];
    }
    pL[tid] = ps;
    __syncthreads();
    if (tid < 16) {
        float c = 0.f;
        #pragma unroll
        for (int jg2 = 0; jg2 < 16; ++jg2) c += pL[jg2 * 16 + tid];
        ctx[(long)(b * 256 + i) * 64 + h * 16 + tid] = c * inv;
    }
}

// ---------- K14: seq_out = seq + ctx@W_outp + b_outp (4 rows/block, W in LDS) ----------
__global__ __launch_bounds__(256) void k14_seqout(
    const float* __restrict__ seq, const float* __restrict__ ctx,
    const float* __restrict__ W_outp, const float* __restrict__ b_outp,
    float* __restrict__ out)
{
    __shared__ float Wo[64 * 64];  // 16 KB
    __shared__ float cL[4][64];
    int tid = threadIdx.x;
    #pragma unroll
    for (int k = 0; k < 16; ++k) Wo[k * 256 + tid] = W_outp[k * 256 + tid];
    int sub = tid >> 6, t = tid & 63;
    int row = blockIdx.x * 4 + sub;
    cL[sub][t] = ctx[row * 64 + t];
    __syncthreads();
    float s = b_outp[t];
    #pragma unroll
    for (int u = 0; u < 64; ++u) s += cL[sub][u] * Wo[u * 64 + t];
    out[row * 64 + t] = seq[row * 64 + t] + s;
}

extern "C" void kernel_launch(void* const* d_in, const int* in_sizes, int n_in,
                              void* d_out, int out_size, void* d_ws, size_t ws_size,
                              hipStream_t stream) {
    const float* seq_repr   = (const float*)d_in[0];
    const float* pair_repr  = (const float*)d_in[1];
    const float* g_attn     = (const float*)d_in[2];
    const float* b_attn     = (const float*)d_in[3];
    const float* g_pair     = (const float*)d_in[4];
    const float* b_pair     = (const float*)d_in[5];
    const float* W_opm_lin  = (const float*)d_in[6];
    const float* b_opm_lin  = (const float*)d_in[7];
    const float* g_opm      = (const float*)d_in[8];
    const float* b_opm      = (const float*)d_in[9];
    const float* W_opm_proj = (const float*)d_in[10];
    const float* b_opm_proj = (const float*)d_in[11];
    const float* W_exp      = (const float*)d_in[12];
    const float* W_dw       = (const float*)d_in[13];
    const float* W_se1      = (const float*)d_in[14];
    const float* b_se1      = (const float*)d_in[15];
    const float* W_se2      = (const float*)d_in[16];
    const float* b_se2      = (const float*)d_in[17];
    const float* W_pw       = (const float*)d_in[18];
    const float* W_qkv      = (const float*)d_in[19];
    const float* W_outp     = (const float*)d_in[20];
    const float* b_outp     = (const float*)d_in[21];
    const float* W_bias     = (const float*)d_in[22];

    float* out_seq  = (float*)d_out;            // 2*256*64 = 32768
    float* out_pair = (float*)d_out + 32768;    // 2*256*256*32

    // Workspace layout (floats). Aliasing: hp aliases e1 (dead after k6_dw);
    // biasb aliases T (dead after k3_op).
    float* w = (float*)d_ws;
    float* a_buf   = w;                    // 16384
    float* am_buf  = a_buf + 16384;        // 512
    float* s2_buf  = am_buf + 512;         // 512
    float* qkv_buf = s2_buf + 512;         // 98304
    float* G_buf   = qkv_buf + 98304;      // 32768
    float* GW_buf  = G_buf + 32768;        // 32
    float* BW_buf  = GW_buf + 32;          // 32
    float* ctx     = BW_buf + 32;          // 32768
    // stats region (memset to 0 each call): 768 floats
    float* st1s    = ctx + 32768;          // 128
    float* st1q    = st1s + 128;           // 128
    float* st2s    = st1q + 128;           // 128
    float* st2q    = st2s + 128;           // 128
    float* st3s    = st2q + 128;           // 64
    float* st3q    = st3s + 64;            // 64
    float* sqs     = st3q + 64;            // 128
    float* sqv     = sqs + 128;            // 128 (written by k9, no zeroing)
    float* T_buf   = sqv + 128;            // 524288
    float* biasb   = T_buf;                // alias
    float* pair1   = T_buf + 524288;       // 4194304
    float* pn      = pair1 + 4194304;      // 4194304
    float* e1      = pn + 4194304;         // 8388608
    float* hp      = e1;                   // alias (4194304)
    float* h2      = e1 + 8388608;         // 8388608

    hipMemsetAsync(st1s, 0, 768 * sizeof(float), stream);

    hipLaunchKernelGGL(k0_prep, dim3(1), dim3(1024), 0, stream,
                       g_opm, b_opm, W_opm_proj, b_opm_proj, G_buf, GW_buf, BW_buf);
    hipLaunchKernelGGL(k1_seq, dim3(128), dim3(256), 0, stream,
                       seq_repr, g_attn, b_attn, W_opm_lin, b_opm_lin, W_qkv,
                       a_buf, am_buf, s2_buf, qkv_buf);
    hipLaunchKernelGGL(k2_T, dim3(512), dim3(256), 0, stream, a_buf, G_buf, T_buf);
    hipLaunchKernelGGL(k3_op, dim3(512), dim3(256), 0, stream,
                       a_buf, am_buf, s2_buf, T_buf, GW_buf, BW_buf,
                       pair_repr, g_pair, b_pair, pair1, pn);
    hipLaunchKernelGGL(k4_expand, dim3(512), dim3(256), 0, stream, pn, W_exp, e1);
    hipLaunchKernelGGL(k_stats, dim3(1024), dim3(256), 0, stream, e1, st1s, st1q);
    hipLaunchKernelGGL(k6_dw, dim3(8192), dim3(256), 0, stream, e1, st1s, st1q, W_dw, h2);
    hipLaunchKernelGGL(k_stats, dim3(1024), dim3(256), 0, stream, h2, st2s, st2q);
    hipLaunchKernelGGL(k8_squeeze, dim3(1024), dim3(256), 0, stream, h2, st2s, st2q, sqs);
    hipLaunchKernelGGL(k9_se, dim3(1), dim3(128), 0, stream,
                       sqs, W_se1, b_se1, W_se2, b_se2, sqv);
    hipLaunchKernelGGL(k10_pw, dim3(512), dim3(256), 0, stream,
                       h2, st2s, st2q, sqv, W_pw, hp);
    hipLaunchKernelGGL(k_stats, dim3(512), dim3(256), 0, stream, hp, st3s, st3q);
    hipLaunchKernelGGL(k12_merge, dim3(512), dim3(256), 0, stream,
                       pair1, pn, hp, st3s, st3q, g_pair, b_pair, W_bias,
                       out_pair, biasb);
    hipLaunchKernelGGL(k13_attn, dim3(2048), dim3(256), 0, stream, qkv_buf, biasb, ctx);
    hipLaunchKernelGGL(k14_seqout, dim3(128), dim3(256), 0, stream,
                       seq_repr, ctx, W_outp, b_outp, out_seq);
}

// Round 4
// 282.740 us; speedup vs baseline: 1.4807x; 1.1643x over previous
//
#include <hip/hip_runtime.h>
#include <hip/hip_bf16.h>

#define LLSZ 65536  // L*L
#define INV_LL (1.f / 65536.f)

// B=2, L=256, SD=64, PD=32, H=4, HD=16, OH=32, EXP=64, SE=16

__device__ __forceinline__ void chan_stats(const float* sum, const float* sumsq,
                                           int chan, float& m, float& isd)
{
    m = sum[chan] * INV_LL;
    float var = sumsq[chan] * INV_LL - m * m;
    isd = rsqrtf(var + 1e-5f);
}

__device__ __forceinline__ float silu(float t) { return t / (1.f + expf(-t)); }

// ---------- K0: prep G[d,e,p]=g_opm[de]*Wproj[de,p], GW[p], BW[p] ----------
__global__ __launch_bounds__(1024) void k0_prep(
    const float* __restrict__ g_opm, const float* __restrict__ b_opm,
    const float* __restrict__ Wproj, const float* __restrict__ b_proj,
    float* __restrict__ G, float* __restrict__ GW, float* __restrict__ BW)
{
    int tid = threadIdx.x;
    int p = tid & 31, rg = tid >> 5;
    float gw = 0.f, bw = 0.f;
    #pragma unroll 4
    for (int k = 0; k < 32; ++k) {
        int de = k * 32 + rg;
        float wv = Wproj[de * 32 + p];
        float gv = g_opm[de] * wv;
        G[de * 32 + p] = gv;
        gw += gv;
        bw += b_opm[de] * wv;
    }
    __shared__ float rG[1024], rB[1024];
    rG[rg * 32 + p] = gw;
    rB[rg * 32 + p] = bw;
    __syncthreads();
    for (int s = 16; s > 0; s >>= 1) {
        if (rg < s) {
            rG[rg * 32 + p] += rG[(rg + s) * 32 + p];
            rB[rg * 32 + p] += rB[(rg + s) * 32 + p];
        }
        __syncthreads();
    }
    if (tid < 32) { GW[p] = rG[p]; BW[p] = rB[p] + b_proj[p]; }
}

// ---------- K1: seq LN -> a (+row stats) and qkv ----------
__global__ __launch_bounds__(256) void k1_seq(
    const float* __restrict__ seq, const float* __restrict__ g_attn,
    const float* __restrict__ b_attn, const float* __restrict__ W_lin,
    const float* __restrict__ b_lin, const float* __restrict__ W_qkv,
    float* __restrict__ a, float* __restrict__ am, float* __restrict__ s2,
    float* __restrict__ qkv)
{
    __shared__ float Wq[64 * 192];
    __shared__ float Wl[64 * 32];
    __shared__ float xL[4][64];
    int tid = threadIdx.x;
    #pragma unroll
    for (int k = 0; k < 48; ++k) Wq[k * 256 + tid] = W_qkv[k * 256 + tid];
    #pragma unroll
    for (int k = 0; k < 8; ++k) Wl[k * 256 + tid] = W_lin[k * 256 + tid];

    int sub = tid >> 6, t = tid & 63;
    int row = blockIdx.x * 4 + sub;
    float v = seq[row * 64 + t];
    float m = v;
    for (int k = 32; k > 0; k >>= 1) m += __shfl_xor(m, k, 64);
    m *= (1.f / 64.f);
    float d = v - m;
    float var = d * d;
    for (int k = 32; k > 0; k >>= 1) var += __shfl_xor(var, k, 64);
    var *= (1.f / 64.f);
    float x = d * rsqrtf(var + 1e-5f) * g_attn[t] + b_attn[t];
    xL[sub][t] = x;
    __syncthreads();

    if (t < 32) {
        float s = 0.f;
        #pragma unroll
        for (int dd = 0; dd < 64; ++dd) s += xL[sub][dd] * Wl[dd * 32 + t];
        s += b_lin[t];
        a[row * 32 + t] = s;
        float mm = s, ss = s * s;
        for (int k = 16; k > 0; k >>= 1) {
            mm += __shfl_xor(mm, k, 32);
            ss += __shfl_xor(ss, k, 32);
        }
        if (t == 0) { am[row] = mm * (1.f / 32.f); s2[row] = ss * (1.f / 32.f); }
    }
    #pragma unroll
    for (int c3 = 0; c3 < 3; ++c3) {
        int c = c3 * 64 + t;
        float s = 0.f;
        #pragma unroll
        for (int dd = 0; dd < 64; ++dd) s += xL[sub][dd] * Wq[dd * 192 + c];
        qkv[row * 192 + c] = s;
    }
}

// ---------- K2: T[row, e*32+p] = sum_d a[row,d]*G[d*1024+e*32+p] ----------
__global__ __launch_bounds__(256) void k2_T(
    const float* __restrict__ a, const float* __restrict__ G, float* __restrict__ T)
{
    int row = blockIdx.x;
    int tid = threadIdx.x;
    __shared__ float aL[32];
    if (tid < 32) aL[tid] = a[row * 32 + tid];
    __syncthreads();
    for (int k = 0; k < 4; ++k) {
        int idx = k * 256 + tid;
        float s = 0.f;
        #pragma unroll
        for (int d = 0; d < 32; ++d) s += aL[d] * G[d * 1024 + idx];
        T[row * 1024 + idx] = s;
    }
}

// ---------- K3: pair1 = pair_repr + op. No barriers in compute; float4 IO ----------
__global__ __launch_bounds__(256) void k3_op(
    const float* __restrict__ a, const float* __restrict__ am,
    const float* __restrict__ s2, const float* __restrict__ T,
    const float* __restrict__ GW, const float* __restrict__ BW,
    const float* __restrict__ pair_in, float* __restrict__ pair1)
{
    int blk = blockIdx.x;           // row*8 + jg
    int row = blk >> 3;             // b*256 + i
    int jg = blk & 7;
    int b = row >> 8;
    int j0 = jg * 32;
    int tid = threadIdx.x;
    __shared__ float Tl[1024];
    __shared__ float aL[32 * 33];
    __shared__ float amL[32], s2L[32], gwL[32], bwL[32];
    ((float4*)Tl)[tid] = ((const float4*)(T + (long)row * 1024))[tid];
    for (int k = 0; k < 4; ++k) {
        int idx = k * 256 + tid;
        aL[(idx >> 5) * 33 + (idx & 31)] = a[(b * 256 + j0) * 32 + idx];
    }
    if (tid < 32) {
        amL[tid] = am[b * 256 + j0 + tid];
        s2L[tid] = s2[b * 256 + j0 + tid];
        gwL[tid] = GW[tid];
        bwL[tid] = BW[tid];
    }
    __syncthreads();
    int jl = tid >> 3, cq = tid & 7;
    float am_i = am[row], s2_i = s2[row];
    float m = am_i * amL[jl];
    float isd = rsqrtf(s2_i * s2L[jl] - m * m + 1e-5f);
    long base = ((long)row * 256 + j0 + jl) * 32 + cq * 4;
    float4 pv = *(const float4*)(pair_in + base);
    float o[4];
    #pragma unroll
    for (int u = 0; u < 4; ++u) {
        int p = cq * 4 + u;
        float S = 0.f;
        #pragma unroll
        for (int e = 0; e < 32; ++e) S += aL[jl * 33 + e] * Tl[e * 32 + p];
        o[u] = isd * (S - m * gwL[p]) + bwL[p];
    }
    pv.x += o[0]; pv.y += o[1]; pv.z += o[2]; pv.w += o[3];
    *(float4*)(pair1 + base) = pv;
}

// ---------- K4: pn = LN(pair1) inline; e1 = pn @ W_exp^T ----------
__global__ __launch_bounds__(256) void k4_expand(
    const float* __restrict__ pair1, const float* __restrict__ g_pair,
    const float* __restrict__ b_pair, const float* __restrict__ W_exp,
    float* __restrict__ e1)
{
    int blk = blockIdx.x;            // b*512 + pg
    int b = blk >> 9;
    int pixbase = (blk & 511) * 128;
    int tid = threadIdx.x;
    __shared__ float pnL[128 * 33];
    __shared__ float We[2048];
    __shared__ float gL[32], bL[32];
    for (int k = 0; k < 8; ++k) We[k * 256 + tid] = W_exp[k * 256 + tid];
    if (tid < 32) { gL[tid] = g_pair[tid]; bL[tid] = b_pair[tid]; }
    const float4* src = (const float4*)(pair1 + ((long)b * LLSZ + pixbase) * 32);
    for (int k = 0; k < 4; ++k) {
        int idx = k * 256 + tid;     // 0..1023 float4s
        int pix = idx >> 3, cq = idx & 7;
        float4 v = src[idx];
        pnL[pix * 33 + cq * 4 + 0] = v.x;
        pnL[pix * 33 + cq * 4 + 1] = v.y;
        pnL[pix * 33 + cq * 4 + 2] = v.z;
        pnL[pix * 33 + cq * 4 + 3] = v.w;
    }
    __syncthreads();
    int pix = tid & 127, og = tid >> 7;
    float s = 0.f, q = 0.f;
    #pragma unroll
    for (int c = 0; c < 32; ++c) { float v = pnL[pix * 33 + c]; s += v; q += v * v; }
    float mu = s * (1.f / 32.f);
    float isd = rsqrtf(q * (1.f / 32.f) - mu * mu + 1e-5f);
    float x[32];
    #pragma unroll
    for (int c = 0; c < 32; ++c) x[c] = (pnL[pix * 33 + c] - mu) * isd * gL[c] + bL[c];
    for (int oo = 0; oo < 32; ++oo) {
        int o = og * 32 + oo;
        float acc = 0.f;
        #pragma unroll
        for (int c = 0; c < 32; ++c) acc += x[c] * We[o * 32 + c];
        e1[((long)(b * 64 + o)) * LLSZ + pixbase + pix] = acc;
    }
}

// ---------- stats: per-channel sum/sumsq, 8 segments + atomics (pre-zeroed) ----------
__global__ __launch_bounds__(256) void k_stats(
    const float* __restrict__ buf, float* __restrict__ sum, float* __restrict__ sumsq)
{
    int bid = blockIdx.x;
    int chan = bid >> 3, seg = bid & 7;
    int tid = threadIdx.x;
    const float4* p = (const float4*)(buf + (long)chan * LLSZ + seg * 8192);
    float s = 0.f, ss = 0.f;
    #pragma unroll
    for (int k = 0; k < 8; ++k) {
        float4 v = p[k * 256 + tid];
        s += v.x + v.y + v.z + v.w;
        ss += v.x * v.x + v.y * v.y + v.z * v.z + v.w * v.w;
    }
    for (int k = 32; k > 0; k >>= 1) { s += __shfl_xor(s, k, 64); ss += __shfl_xor(ss, k, 64); }
    __shared__ float rs[4], rq[4];
    int wave = tid >> 6;
    if ((tid & 63) == 0) { rs[wave] = s; rq[wave] = ss; }
    __syncthreads();
    if (tid == 0) {
        atomicAdd(&sum[chan], rs[0] + rs[1] + rs[2] + rs[3]);
        atomicAdd(&sumsq[chan], rq[0] + rq[1] + rq[2] + rq[3]);
    }
}

// ---------- K6: depthwise 3x3 on silu(inorm(e1)) -> h2. Row-staged, float4 ----------
__global__ __launch_bounds__(256) void k6_dw(
    const float* __restrict__ e1, const float* __restrict__ st1s,
    const float* __restrict__ st1q, const float* __restrict__ W_dw,
    float* __restrict__ h2)
{
    int blk = blockIdx.x;            // chan*32 + rg
    int chan = blk >> 5;             // 0..127
    int r0 = (blk & 31) * 8;
    int o = chan & 63;
    int tid = threadIdx.x;
    float m, isd;
    chan_stats(st1s, st1q, chan, m, isd);
    __shared__ float sL[10][258];
    const float* src = e1 + (long)chan * LLSZ;
    for (int k = tid; k < 640; k += 256) {   // 10 rows x 64 float4
        int rr = k >> 6, c4 = k & 63;
        int g = r0 - 1 + rr;
        float4 v = make_float4(0.f, 0.f, 0.f, 0.f);
        if (g >= 0 && g < 256) v = *(const float4*)(src + g * 256 + c4 * 4);
        float t;
        t = (v.x - m) * isd; v.x = (g >= 0 && g < 256) ? silu(t) : 0.f;
        t = (v.y - m) * isd; v.y = (g >= 0 && g < 256) ? silu(t) : 0.f;
        t = (v.z - m) * isd; v.z = (g >= 0 && g < 256) ? silu(t) : 0.f;
        t = (v.w - m) * isd; v.w = (g >= 0 && g < 256) ? silu(t) : 0.f;
        sL[rr][1 + c4 * 4 + 0] = v.x;
        sL[rr][1 + c4 * 4 + 1] = v.y;
        sL[rr][1 + c4 * 4 + 2] = v.z;
        sL[rr][1 + c4 * 4 + 3] = v.w;
    }
    if (tid < 10) { sL[tid][0] = 0.f; sL[tid][257] = 0.f; }
    float w[9];
    #pragma unroll
    for (int k = 0; k < 9; ++k) w[k] = W_dw[o * 9 + k];
    __syncthreads();
    int c = tid;  // column 0..255
    #pragma unroll
    for (int rr = 0; rr < 8; ++rr) {
        float s = 0.f;
        #pragma unroll
        for (int ki = 0; ki < 3; ++ki)
            #pragma unroll
            for (int kj = 0; kj < 3; ++kj)
                s += sL[rr + ki][c + kj] * w[ki * 3 + kj];
        h2[(long)chan * LLSZ + (r0 + rr) * 256 + c] = s;
    }
}

// ---------- K8: squeeze-sum of silu(inorm(h2)) ----------
__global__ __launch_bounds__(256) void k8_squeeze(
    const float* __restrict__ h2, const float* __restrict__ st2s,
    const float* __restrict__ st2q, float* __restrict__ sqs)
{
    int bid = blockIdx.x;
    int chan = bid >> 3, seg = bid & 7;
    int tid = threadIdx.x;
    float m, isd;
    chan_stats(st2s, st2q, chan, m, isd);
    const float4* p = (const float4*)(h2 + (long)chan * LLSZ + seg * 8192);
    float s = 0.f;
    #pragma unroll
    for (int k = 0; k < 8; ++k) {
        float4 v = p[k * 256 + tid];
        s += silu((v.x - m) * isd) + silu((v.y - m) * isd)
           + silu((v.z - m) * isd) + silu((v.w - m) * isd);
    }
    for (int k = 32; k > 0; k >>= 1) s += __shfl_xor(s, k, 64);
    __shared__ float rs[4];
    int wave = tid >> 6;
    if ((tid & 63) == 0) rs[wave] = s;
    __syncthreads();
    if (tid == 0) atomicAdd(&sqs[chan], rs[0] + rs[1] + rs[2] + rs[3]);
}

// ---------- K10: SE-MLP (inline) + pointwise conv + stats3 fusion ----------
__global__ __launch_bounds__(256) void k10_pw(
    const float* __restrict__ h2, const float* __restrict__ st2s,
    const float* __restrict__ st2q, const float* __restrict__ sqs,
    const float* __restrict__ W_se1, const float* __restrict__ b_se1,
    const float* __restrict__ W_se2, const float* __restrict__ b_se2,
    const float* __restrict__ W_pw, float* __restrict__ hp,
    float* __restrict__ st3s, float* __restrict__ st3q)
{
    int blk = blockIdx.x;
    int b = blk >> 8;
    int pixbase = (blk & 255) * 256;
    int tid = threadIdx.x;
    __shared__ float hL[32 * 256];
    __shared__ float Wp[2048];
    __shared__ float s1L[16];
    __shared__ float sqvL[64];
    __shared__ float red[4][32], redq[4][32];
    for (int k = 0; k < 8; ++k) Wp[k * 256 + tid] = W_pw[k * 256 + tid];
    if (tid < 16) {
        float s = 0.f;
        for (int c = 0; c < 64; ++c) s += sqs[b * 64 + c] * W_se1[tid * 64 + c];
        s = s * INV_LL + b_se1[tid];
        s1L[tid] = silu(s);
    }
    __syncthreads();
    if (tid < 64) {
        float s = 0.f;
        #pragma unroll
        for (int j = 0; j < 16; ++j) s += s1L[j] * W_se2[tid * 16 + j];
        s += b_se2[tid];
        sqvL[tid] = 1.f / (1.f + expf(-s));
    }
    float acc[32];
    #pragma unroll
    for (int p = 0; p < 32; ++p) acc[p] = 0.f;
    for (int half = 0; half < 2; ++half) {
        __syncthreads();
        for (int k = 0; k < 8; ++k) {
            int idx = k * 256 + tid;
            int c = idx >> 6, q4 = idx & 63;
            int chan = b * 64 + half * 32 + c;
            float m, isd;
            chan_stats(st2s, st2q, chan, m, isd);
            float sc = sqvL[half * 32 + c];
            float4 v = *(const float4*)(h2 + (long)chan * LLSZ + pixbase + q4 * 4);
            v.x = silu((v.x - m) * isd) * sc;
            v.y = silu((v.y - m) * isd) * sc;
            v.z = silu((v.z - m) * isd) * sc;
            v.w = silu((v.w - m) * isd) * sc;
            *(float4*)(hL + c * 256 + q4 * 4) = v;
        }
        __syncthreads();
        #pragma unroll
        for (int p = 0; p < 32; ++p) {
            float s = 0.f;
            #pragma unroll
            for (int c = 0; c < 32; ++c) s += hL[c * 256 + tid] * Wp[p * 64 + half * 32 + c];
            acc[p] += s;
        }
    }
    int wave = tid >> 6, lane = tid & 63;
    #pragma unroll
    for (int p = 0; p < 32; ++p) {
        float v = acc[p];
        hp[((long)(b * 32 + p)) * LLSZ + pixbase + tid] = v;
        float s = v, q = v * v;
        for (int k = 32; k > 0; k >>= 1) { s += __shfl_xor(s, k, 64); q += __shfl_xor(q, k, 64); }
        if (lane == 0) { red[wave][p] = s; redq[wave][p] = q; }
    }
    __syncthreads();
    if (tid < 32) {
        atomicAdd(&st3s[b * 32 + tid], red[0][tid] + red[1][tid] + red[2][tid] + red[3][tid]);
        atomicAdd(&st3q[b * 32 + tid], redq[0][tid] + redq[1][tid] + redq[2][tid] + redq[3][tid]);
    }
}

// ---------- K12: pair_out = pair1 + LN(pair1) + inorm(hp); bias = LN(pair_out)@W_bias ----------
__global__ __launch_bounds__(256) void k12_merge(
    const float* __restrict__ pair1, const float* __restrict__ hp,
    const float* __restrict__ st3s, const float* __restrict__ st3q,
    const float* __restrict__ g_pair, const float* __restrict__ b_pair,
    const float* __restrict__ W_bias, float* __restrict__ pair_out,
    float* __restrict__ biasbuf)
{
    int blk = blockIdx.x;
    int b = blk >> 8;
    int pixbase = (blk & 255) * 256;
    int tid = threadIdx.x;
    __shared__ float hpL[32][257];
    for (int k = 0; k < 8; ++k) {
        int idx = k * 256 + tid;
        int p = idx >> 6, q4 = idx & 63;
        int chan = b * 32 + p;
        float m, isd;
        chan_stats(st3s, st3q, chan, m, isd);
        float4 v = *(const float4*)(hp + (long)chan * LLSZ + pixbase + q4 * 4);
        hpL[p][q4 * 4 + 0] = (v.x - m) * isd;
        hpL[p][q4 * 4 + 1] = (v.y - m) * isd;
        hpL[p][q4 * 4 + 2] = (v.z - m) * isd;
        hpL[p][q4 * 4 + 3] = (v.w - m) * isd;
    }
    __syncthreads();
    int pg = tid >> 3, cq = tid & 7;
    float gp[4], bp[4], wb[4][4];
    #pragma unroll
    for (int u = 0; u < 4; ++u) {
        int c = cq * 4 + u;
        gp[u] = g_pair[c]; bp[u] = b_pair[c];
        #pragma unroll
        for (int h = 0; h < 4; ++h) wb[u][h] = W_bias[c * 4 + h];
    }
    for (int it = 0; it < 8; ++it) {
        int pix = it * 32 + pg;
        long base = ((long)b * LLSZ + pixbase + pix) * 32;
        float4 v1 = *(const float4*)(pair1 + base + cq * 4);
        float s = v1.x + v1.y + v1.z + v1.w;
        float q = v1.x * v1.x + v1.y * v1.y + v1.z * v1.z + v1.w * v1.w;
        s += __shfl_xor(s, 1, 8); q += __shfl_xor(q, 1, 8);
        s += __shfl_xor(s, 2, 8); q += __shfl_xor(q, 2, 8);
        s += __shfl_xor(s, 4, 8); q += __shfl_xor(q, 4, 8);
        float mu = s * (1.f / 32.f);
        float isd = rsqrtf(q * (1.f / 32.f) - mu * mu + 1e-5f);
        float vo[4], vv1[4] = {v1.x, v1.y, v1.z, v1.w};
        #pragma unroll
        for (int u = 0; u < 4; ++u) {
            float pnv = (vv1[u] - mu) * isd * gp[u] + bp[u];
            vo[u] = vv1[u] + pnv + hpL[cq * 4 + u][pix];
        }
        float4 vout = make_float4(vo[0], vo[1], vo[2], vo[3]);
        *(float4*)(pair_out + base + cq * 4) = vout;
        float s2_ = vo[0] + vo[1] + vo[2] + vo[3];
        float q2 = vo[0] * vo[0] + vo[1] * vo[1] + vo[2] * vo[2] + vo[3] * vo[3];
        s2_ += __shfl_xor(s2_, 1, 8); q2 += __shfl_xor(q2, 1, 8);
        s2_ += __shfl_xor(s2_, 2, 8); q2 += __shfl_xor(q2, 2, 8);
        s2_ += __shfl_xor(s2_, 4, 8); q2 += __shfl_xor(q2, 4, 8);
        float mu2 = s2_ * (1.f / 32.f);
        float isd2 = rsqrtf(q2 * (1.f / 32.f) - mu2 * mu2 + 1e-5f);
        float t[4] = {0.f, 0.f, 0.f, 0.f};
        #pragma unroll
        for (int u = 0; u < 4; ++u) {
            float pn2 = (vo[u] - mu2) * isd2 * gp[u] + bp[u];
            #pragma unroll
            for (int h = 0; h < 4; ++h) t[h] += pn2 * wb[u][h];
        }
        #pragma unroll
        for (int h = 0; h < 4; ++h) {
            t[h] += __shfl_xor(t[h], 1, 8);
            t[h] += __shfl_xor(t[h], 2, 8);
            t[h] += __shfl_xor(t[h], 4, 8);
        }
        if (cq == 0) {
            #pragma unroll
            for (int h = 0; h < 4; ++h)
                biasbuf[((long)(b * 4 + h)) * LLSZ + pixbase + pix] = t[h];
        }
    }
}

// ---------- K13: attention, one wave per (b,h,i), no barriers ----------
__global__ __launch_bounds__(256) void k13_attn(
    const float* __restrict__ qkv, const float* __restrict__ biasbuf,
    float* __restrict__ ctx)
{
    int blk = blockIdx.x;           // b*256 + h*64 + ig
    int b = blk >> 8;
    int h = (blk >> 6) & 3;
    int ig = blk & 63;
    int wave = threadIdx.x >> 6, lane = threadIdx.x & 63;
    int i = ig * 4 + wave;
    const float* qrow = qkv + ((long)(b * 256 + i)) * 192 + h * 16;
    float qv[16];
    #pragma unroll
    for (int d = 0; d < 16; ++d) qv[d] = qrow[d];
    float sj[4];
    #pragma unroll
    for (int q = 0; q < 4; ++q) {
        int j = lane + 64 * q;
        const float* kr = qkv + ((long)(b * 256 + j)) * 192 + 64 + h * 16;
        float s = 0.f;
        #pragma unroll
        for (int d = 0; d < 16; ++d) s += qv[d] * kr[d];
        sj[q] = s * 0.25f + biasbuf[((long)(b * 4 + h)) * LLSZ + i * 256 + j];
    }
    float mx = fmaxf(fmaxf(sj[0], sj[1]), fmaxf(sj[2], sj[3]));
    for (int k = 32; k > 0; k >>= 1) mx = fmaxf(mx, __shfl_xor(mx, k, 64));
    float wgt[4], wsum = 0.f;
    #pragma unroll
    for (int q = 0; q < 4; ++q) { wgt[q] = expf(sj[q] - mx); wsum += wgt[q]; }
    for (int k = 32; k > 0; k >>= 1) wsum += __shfl_xor(wsum, k, 64);
    float inv = 1.f / wsum;
    float o[16];
    #pragma unroll
    for (int d = 0; d < 16; ++d) o[d] = 0.f;
    #pragma unroll
    for (int q = 0; q < 4; ++q) {
        const float* vr = qkv + ((long)(b * 256 + lane + 64 * q)) * 192 + 128 + h * 16;
        #pragma unroll
        for (int d = 0; d < 16; ++d) o[d] += wgt[q] * vr[d];
    }
    #pragma unroll
    for (int d = 0; d < 16; ++d)
        for (int k = 32; k > 0; k >>= 1) o[d] += __shfl_xor(o[d], k, 64);
    if (lane == 0) {
        #pragma unroll
        for (int d = 0; d < 16; ++d)
            ctx[((long)(b * 256 + i)) * 64 + h * 16 + d] = o[d] * inv;
    }
}

// ---------- K14: seq_out = seq + ctx@W_outp + b_outp ----------
__global__ __launch_bounds__(256) void k14_seqout(
    const float* __restrict__ seq, const float* __restrict__ ctx,
    const float* __restrict__ W_outp, const float* __restrict__ b_outp,
    float* __restrict__ out)
{
    __shared__ float Wo[64 * 64];
    __shared__ float cL[4][64];
    int tid = threadIdx.x;
    #pragma unroll
    for (int k = 0; k < 16; ++k) Wo[k * 256 + tid] = W_outp[k * 256 + tid];
    int sub = tid >> 6, t = tid & 63;
    int row = blockIdx.x * 4 + sub;
    cL[sub][t] = ctx[row * 64 + t];
    __syncthreads();
    float s = b_outp[t];
    #pragma unroll
    for (int u = 0; u < 64; ++u) s += cL[sub][u] * Wo[u * 64 + t];
    out[row * 64 + t] = seq[row * 64 + t] + s;
}

extern "C" void kernel_launch(void* const* d_in, const int* in_sizes, int n_in,
                              void* d_out, int out_size, void* d_ws, size_t ws_size,
                              hipStream_t stream) {
    const float* seq_repr   = (const float*)d_in[0];
    const float* pair_repr  = (const float*)d_in[1];
    const float* g_attn     = (const float*)d_in[2];
    const float* b_attn     = (const float*)d_in[3];
    const float* g_pair     = (const float*)d_in[4];
    const float* b_pair     = (const float*)d_in[5];
    const float* W_opm_lin  = (const float*)d_in[6];
    const float* b_opm_lin  = (const float*)d_in[7];
    const float* g_opm      = (const float*)d_in[8];
    const float* b_opm      = (const float*)d_in[9];
    const float* W_opm_proj = (const float*)d_in[10];
    const float* b_opm_proj = (const float*)d_in[11];
    const float* W_exp      = (const float*)d_in[12];
    const float* W_dw       = (const float*)d_in[13];
    const float* W_se1      = (const float*)d_in[14];
    const float* b_se1      = (const float*)d_in[15];
    const float* W_se2      = (const float*)d_in[16];
    const float* b_se2      = (const float*)d_in[17];
    const float* W_pw       = (const float*)d_in[18];
    const float* W_qkv      = (const float*)d_in[19];
    const float* W_outp     = (const float*)d_in[20];
    const float* b_outp     = (const float*)d_in[21];
    const float* W_bias     = (const float*)d_in[22];

    float* out_seq  = (float*)d_out;
    float* out_pair = (float*)d_out + 32768;

    // Workspace (floats). hp aliases e1 (dead after k6); biasb aliases T (dead after k3).
    float* w = (float*)d_ws;
    float* a_buf   = w;                    // 16384
    float* am_buf  = a_buf + 16384;        // 512
    float* s2_buf  = am_buf + 512;         // 512
    float* qkv_buf = s2_buf + 512;         // 98304
    float* G_buf   = qkv_buf + 98304;      // 32768
    float* GW_buf  = G_buf + 32768;        // 32
    float* BW_buf  = GW_buf + 32;          // 32
    float* ctx     = BW_buf + 32;          // 32768
    float* st1s    = ctx + 32768;          // 128  } memset region
    float* st1q    = st1s + 128;           // 128
    float* st2s    = st1q + 128;           // 128
    float* st2q    = st2s + 128;           // 128
    float* st3s    = st2q + 128;           // 64
    float* st3q    = st3s + 64;            // 64
    float* sqs     = st3q + 64;            // 128  } total 768
    float* T_buf   = sqs + 128;            // 524288
    float* biasb   = T_buf;                // alias
    float* pair1   = T_buf + 524288;       // 4194304
    float* e1      = pair1 + 4194304;      // 8388608
    float* hp      = e1;                   // alias (4194304)
    float* h2      = e1 + 8388608;         // 8388608

    hipMemsetAsync(st1s, 0, 768 * sizeof(float), stream);

    hipLaunchKernelGGL(k0_prep, dim3(1), dim3(1024), 0, stream,
                       g_opm, b_opm, W_opm_proj, b_opm_proj, G_buf, GW_buf, BW_buf);
    hipLaunchKernelGGL(k1_seq, dim3(128), dim3(256), 0, stream,
                       seq_repr, g_attn, b_attn, W_opm_lin, b_opm_lin, W_qkv,
                       a_buf, am_buf, s2_buf, qkv_buf);
    hipLaunchKernelGGL(k2_T, dim3(512), dim3(256), 0, stream, a_buf, G_buf, T_buf);
    hipLaunchKernelGGL(k3_op, dim3(4096), dim3(256), 0, stream,
                       a_buf, am_buf, s2_buf, T_buf, GW_buf, BW_buf,
                       pair_repr, pair1);
    hipLaunchKernelGGL(k4_expand, dim3(1024), dim3(256), 0, stream,
                       pair1, g_pair, b_pair, W_exp, e1);
    hipLaunchKernelGGL(k_stats, dim3(1024), dim3(256), 0, stream, e1, st1s, st1q);
    hipLaunchKernelGGL(k6_dw, dim3(4096), dim3(256), 0, stream,
                       e1, st1s, st1q, W_dw, h2);
    hipLaunchKernelGGL(k_stats, dim3(1024), dim3(256), 0, stream, h2, st2s, st2q);
    hipLaunchKernelGGL(k8_squeeze, dim3(1024), dim3(256), 0, stream,
                       h2, st2s, st2q, sqs);
    hipLaunchKernelGGL(k10_pw, dim3(512), dim3(256), 0, stream,
                       h2, st2s, st2q, sqs, W_se1, b_se1, W_se2, b_se2,
                       W_pw, hp, st3s, st3q);
    hipLaunchKernelGGL(k12_merge, dim3(512), dim3(256), 0, stream,
                       pair1, hp, st3s, st3q, g_pair, b_pair, W_bias,
                       out_pair, biasb);
    hipLaunchKernelGGL(k13_attn, dim3(512), dim3(256), 0, stream,
                       qkv_buf, biasb, ctx);
    hipLaunchKernelGGL(k14_seqout, dim3(128), dim3(256), 0, stream,
                       seq_repr, ctx, W_outp, b_outp, out_seq);
}